// Round 9
// baseline (6294.945 us; speedup 1.0000x reference)
//
#include <hip/hip_runtime.h>

#define TT 512
#define HH 256
#define BB 128

typedef unsigned long long u64;

// 256 wgs x 1024 threads, cooperative, 1 wg/CU (forced by >80KB static LDS).
// Group g (= wg & 31) = wgs {g, g+32, ..., g+224}, batches 4g..4g+3.
// Member q = wg>>5 owns h elements [32q,32q+32) (gate rows G*256+32q+[0,32)).
// Thread holds 2 rows x 16 K = 32 weight floats in VGPRs (64-VGPR budget).
//
// Round-9 structure: dot waves ds_add_f32 partials straight into a padded
// gates[] LDS region (no part_lds, no reduce phase, 2 barriers/step);
// exchange via epoch-tagged 8B payloads {epoch,h}, agent-scope relaxed
// atomics (proven round-5 semantics), coalesced 256B publish bursts.
__global__ __launch_bounds__(1024)
__attribute__((amdgpu_waves_per_eu(4, 4)))
void lstm_coop(
    const float* __restrict__ x,      // [B,T]
    const float* __restrict__ W_ih,   // [1024]
    const float* __restrict__ W_hh,   // [1024,256]
    const float* __restrict__ b_ih,   // [1024]
    const float* __restrict__ b_hh,   // [1024]
    const float* __restrict__ W1,     // [128,256]
    const float* __restrict__ b1,     // [128]
    const float* __restrict__ W2,     // [128]
    const float* __restrict__ b2,     // [1]
    float* __restrict__ out,          // [B]
    u64* __restrict__ hpair)          // [2][BB][HH] {epoch,h}
{
    const int wg  = blockIdx.x;
    const int g   = wg & 31;          // group id
    const int q   = wg >> 5;          // member 0..7
    const int tid = threadIdx.x;
    const int b0  = 4 * g;

    __shared__ float x_lds[4][TT];        // 8 KB
    __shared__ float h_lds[4][HH];        // 4 KB
    __shared__ float red_lds[4][128];     // 2 KB
    __shared__ float cc_lds[128][8];      // 4 KB  cell consts (4 wih + 4 bias)
    // gates live in big[row*5 + m], row in [0,128), m in [0,4) (stride 5 ->
    // conflict-free ds_add). Oversized so static LDS > 80KB => 1 wg/CU.
    __shared__ float big[25600];          // 100 KB

    const int s  = tid >> 6;          // 0..15 : K-chunk of 16
    const int r2 = tid & 63;          // row pair: local rows r2 and r2+64
    const int lA = r2, lB = r2 + 64;
    const int RA = (lA >> 5) * HH + q * 32 + (lA & 31);
    const int RB = (lB >> 5) * HH + q * 32 + (lB & 31);

    // resident weights: 2 rows x 16 K = 32 VGPRs
    float wA[16], wB[16];
    {
        const float4* pa = reinterpret_cast<const float4*>(W_hh + (size_t)RA * HH + 16 * s);
        const float4* pb = reinterpret_cast<const float4*>(W_hh + (size_t)RB * HH + 16 * s);
        #pragma unroll
        for (int k = 0; k < 4; ++k) {
            float4 va = pa[k], vb = pb[k];
            wA[4*k+0] = va.x; wA[4*k+1] = va.y; wA[4*k+2] = va.z; wA[4*k+3] = va.w;
            wB[4*k+0] = vb.x; wB[4*k+1] = vb.y; wB[4*k+2] = vb.z; wB[4*k+3] = vb.w;
        }
    }
    #pragma unroll
    for (int k = 0; k < 16; ++k) {
        asm volatile("" : "+v"(wA[k]));
        asm volatile("" : "+v"(wB[k]));
    }

    // stage x for 4 batches (2048 elems, 2 per thread)
    #pragma unroll
    for (int u = 0; u < 2; ++u) {
        int idx = tid + u * 1024;
        int m = idx >> 9, j = idx & 511;
        x_lds[m][j] = x[(size_t)(b0 + m) * TT + j];
    }
    // h init
    h_lds[tid >> 8][tid & 255] = 0.0f;
    // gates zero-init
    if (tid < 640) big[tid] = 0.0f;
    // cell constants: thread tid<128 handles element l = tid&31 of batch m = tid>>5
    if (tid < 128) {
        const int l = tid & 31;
        #pragma unroll
        for (int G = 0; G < 4; ++G) {
            const int R = G * HH + q * 32 + l;
            cc_lds[tid][G]     = W_ih[R];
            cc_lds[tid][4 + G] = b_ih[R] + b_hh[R];
        }
    }

    float c = 0.0f;                   // cell state for tid<128
    __syncthreads();

    for (int t = 0; t < TT; ++t) {
        // ---- dot: 2 rows x 16 K x 4 batches = 128 FMA from registers
        float accA[4], accB[4];
        #pragma unroll
        for (int m = 0; m < 4; ++m) {
            const float4* hm = reinterpret_cast<const float4*>(&h_lds[m][16 * s]);
            float4 h0 = hm[0], h1 = hm[1], h2 = hm[2], h3 = hm[3];
            float aa, ab;
            aa = wA[0] * h0.x;                     ab = wB[0] * h0.x;
            aa = __builtin_fmaf(wA[1],  h0.y, aa); ab = __builtin_fmaf(wB[1],  h0.y, ab);
            aa = __builtin_fmaf(wA[2],  h0.z, aa); ab = __builtin_fmaf(wB[2],  h0.z, ab);
            aa = __builtin_fmaf(wA[3],  h0.w, aa); ab = __builtin_fmaf(wB[3],  h0.w, ab);
            aa = __builtin_fmaf(wA[4],  h1.x, aa); ab = __builtin_fmaf(wB[4],  h1.x, ab);
            aa = __builtin_fmaf(wA[5],  h1.y, aa); ab = __builtin_fmaf(wB[5],  h1.y, ab);
            aa = __builtin_fmaf(wA[6],  h1.z, aa); ab = __builtin_fmaf(wB[6],  h1.z, ab);
            aa = __builtin_fmaf(wA[7],  h1.w, aa); ab = __builtin_fmaf(wB[7],  h1.w, ab);
            aa = __builtin_fmaf(wA[8],  h2.x, aa); ab = __builtin_fmaf(wB[8],  h2.x, ab);
            aa = __builtin_fmaf(wA[9],  h2.y, aa); ab = __builtin_fmaf(wB[9],  h2.y, ab);
            aa = __builtin_fmaf(wA[10], h2.z, aa); ab = __builtin_fmaf(wB[10], h2.z, ab);
            aa = __builtin_fmaf(wA[11], h2.w, aa); ab = __builtin_fmaf(wB[11], h2.w, ab);
            aa = __builtin_fmaf(wA[12], h3.x, aa); ab = __builtin_fmaf(wB[12], h3.x, ab);
            aa = __builtin_fmaf(wA[13], h3.y, aa); ab = __builtin_fmaf(wB[13], h3.y, ab);
            aa = __builtin_fmaf(wA[14], h3.z, aa); ab = __builtin_fmaf(wB[14], h3.z, ab);
            aa = __builtin_fmaf(wA[15], h3.w, aa); ab = __builtin_fmaf(wB[15], h3.w, ab);
            accA[m] = aa; accB[m] = ab;
        }
        // fused reduction: ds_add_f32 into gates (stride-5 rows)
        #pragma unroll
        for (int m = 0; m < 4; ++m) {
            atomicAdd(&big[lA * 5 + m], accA[m]);
            atomicAdd(&big[lB * 5 + m], accB[m]);
        }
        __syncthreads();

        const int p = (t + 1) & 1;

        // ---- cell update + publish: 128 threads (m = tid>>5, l = tid&31)
        if (tid < 128) {
            const int m = tid >> 5;
            const int l = tid & 31;
            float ig = big[(     l) * 5 + m];
            float fg = big[(32 + l) * 5 + m];
            float gg = big[(64 + l) * 5 + m];
            float og = big[(96 + l) * 5 + m];
            // re-zero for next step (this thread is the unique reader)
            big[(     l) * 5 + m] = 0.0f;
            big[(32 + l) * 5 + m] = 0.0f;
            big[(64 + l) * 5 + m] = 0.0f;
            big[(96 + l) * 5 + m] = 0.0f;
            const float xv = x_lds[m][t];
            const int cc = (m << 5) | l;   // NOTE: cc index = tid (same mapping)
            ig += __builtin_fmaf(xv, cc_lds[cc][0], cc_lds[cc][4]);
            fg += __builtin_fmaf(xv, cc_lds[cc][1], cc_lds[cc][5]);
            gg += __builtin_fmaf(xv, cc_lds[cc][2], cc_lds[cc][6]);
            og += __builtin_fmaf(xv, cc_lds[cc][3], cc_lds[cc][7]);
            ig = __builtin_amdgcn_rcpf(1.f + __expf(-ig));
            fg = __builtin_amdgcn_rcpf(1.f + __expf(-fg));
            og = __builtin_amdgcn_rcpf(1.f + __expf(-og));
            gg = 2.f * __builtin_amdgcn_rcpf(1.f + __expf(-2.f * gg)) - 1.f;
            c = __builtin_fmaf(fg, c, ig * gg);
            float th = 2.f * __builtin_amdgcn_rcpf(1.f + __expf(-2.f * c)) - 1.f;
            float hn = og * th;
            const int e = q * 32 + l;
            u64 pk = ((u64)(unsigned)(t + 1) << 32) | (u64)__float_as_uint(hn);
            __hip_atomic_store(&hpair[((size_t)p * BB + (b0 + m)) * HH + e], pk,
                               __ATOMIC_RELAXED, __HIP_MEMORY_SCOPE_AGENT);
        }

        // ---- import h (epoch t+1): every thread one (m,j) payload (coalesced)
        {
            const int m = tid >> 8, j = tid & 255;
            u64* src = &hpair[((size_t)p * BB + (b0 + m)) * HH + j];
            u64 v = __hip_atomic_load(src, __ATOMIC_RELAXED, __HIP_MEMORY_SCOPE_AGENT);
            int spins = 0;
            while ((unsigned)(v >> 32) < (unsigned)(t + 1)) {
                ++spins;
                if (spins > 32)     __builtin_amdgcn_s_sleep(4);
                else if (spins > 4) __builtin_amdgcn_s_sleep(1);
                v = __hip_atomic_load(src, __ATOMIC_RELAXED, __HIP_MEMORY_SCOPE_AGENT);
            }
            h_lds[m][j] = __uint_as_float((unsigned)v);
        }
        __syncthreads();
    }

    // ---- epilogue: h_lds holds final h (epoch TT); q==0 runs the MLP
    if (q == 0) {
        if (tid < 512) {
            const int m = tid >> 7, j = tid & 127;
            const float4* w1p = reinterpret_cast<const float4*>(W1 + (size_t)j * HH);
            const float4* hp  = reinterpret_cast<const float4*>(&h_lds[m][0]);
            float s0 = 0.f, s1 = 0.f, s2 = 0.f, s3 = 0.f;
            #pragma unroll
            for (int k = 0; k < 64; ++k) {
                float4 wv = w1p[k], hv = hp[k];
                s0 = __builtin_fmaf(wv.x, hv.x, s0);
                s1 = __builtin_fmaf(wv.y, hv.y, s1);
                s2 = __builtin_fmaf(wv.z, hv.z, s2);
                s3 = __builtin_fmaf(wv.w, hv.w, s3);
            }
            float rv = fmaxf((s0 + s1) + (s2 + s3) + b1[j], 0.f);
            red_lds[m][j] = rv * W2[j];
        }
        __syncthreads();
        if (tid < 4) {
            float y = b2[0];
            for (int k = 0; k < 128; ++k) y += red_lds[tid][k];
            out[b0 + tid] = y;
        }
    }
}

extern "C" void kernel_launch(void* const* d_in, const int* in_sizes, int n_in,
                              void* d_out, int out_size, void* d_ws, size_t ws_size,
                              hipStream_t stream) {
    const float* x    = (const float*)d_in[0];
    const float* W_ih = (const float*)d_in[1];
    const float* W_hh = (const float*)d_in[2];
    const float* b_ih = (const float*)d_in[3];
    const float* b_hh = (const float*)d_in[4];
    const float* W1   = (const float*)d_in[5];
    const float* b1   = (const float*)d_in[6];
    const float* W2   = (const float*)d_in[7];
    const float* b2   = (const float*)d_in[8];
    float* out  = (float*)d_out;

    u64* hpair = (u64*)d_ws;                    // [2][128][256] x 8B = 512 KB

    // epochs must be 0 at every call (d_ws persists across graph replays)
    (void)hipMemsetAsync(d_ws, 0, (size_t)2 * BB * HH * sizeof(u64), stream);

    void* args[] = {(void*)&x, (void*)&W_ih, (void*)&W_hh, (void*)&b_ih, (void*)&b_hh,
                    (void*)&W1, (void*)&b1, (void*)&W2, (void*)&b2,
                    (void*)&out, (void*)&hpair};
    (void)hipLaunchCooperativeKernel((void*)lstm_coop, dim3(256), dim3(1024), args, 0, stream);
}

// Round 10
// 1650.066 us; speedup vs baseline: 3.8150x; 3.8150x over previous
//
#include <hip/hip_runtime.h>

#define TT 512
#define HH 256
#define BB 128

typedef unsigned long long u64;

// 16 FMAs of two weight rows against one 16-wide h chunk.
__device__ __forceinline__ void dot2x16(const float* h,
                                        const float* wa_, const float* wb_,
                                        float& ra, float& rb) {
    float4 p0 = *(const float4*)(h);
    float4 p1 = *(const float4*)(h + 4);
    float4 p2 = *(const float4*)(h + 8);
    float4 p3 = *(const float4*)(h + 12);
    float a, b;
    a = wa_[0] * p0.x;                    b = wb_[0] * p0.x;
    a = __builtin_fmaf(wa_[1],  p0.y, a); b = __builtin_fmaf(wb_[1],  p0.y, b);
    a = __builtin_fmaf(wa_[2],  p0.z, a); b = __builtin_fmaf(wb_[2],  p0.z, b);
    a = __builtin_fmaf(wa_[3],  p0.w, a); b = __builtin_fmaf(wb_[3],  p0.w, b);
    a = __builtin_fmaf(wa_[4],  p1.x, a); b = __builtin_fmaf(wb_[4],  p1.x, b);
    a = __builtin_fmaf(wa_[5],  p1.y, a); b = __builtin_fmaf(wb_[5],  p1.y, b);
    a = __builtin_fmaf(wa_[6],  p1.z, a); b = __builtin_fmaf(wb_[6],  p1.z, b);
    a = __builtin_fmaf(wa_[7],  p1.w, a); b = __builtin_fmaf(wb_[7],  p1.w, b);
    a = __builtin_fmaf(wa_[8],  p2.x, a); b = __builtin_fmaf(wb_[8],  p2.x, b);
    a = __builtin_fmaf(wa_[9],  p2.y, a); b = __builtin_fmaf(wb_[9],  p2.y, b);
    a = __builtin_fmaf(wa_[10], p2.z, a); b = __builtin_fmaf(wb_[10], p2.z, b);
    a = __builtin_fmaf(wa_[11], p2.w, a); b = __builtin_fmaf(wb_[11], p2.w, b);
    a = __builtin_fmaf(wa_[12], p3.x, a); b = __builtin_fmaf(wb_[12], p3.x, b);
    a = __builtin_fmaf(wa_[13], p3.y, a); b = __builtin_fmaf(wb_[13], p3.y, b);
    a = __builtin_fmaf(wa_[14], p3.z, a); b = __builtin_fmaf(wb_[14], p3.z, b);
    a = __builtin_fmaf(wa_[15], p3.w, a); b = __builtin_fmaf(wb_[15], p3.w, b);
    ra = a; rb = b;
}

// 256 wgs x 1024 threads, cooperative, 1 wg/CU (forced by >80KB static LDS).
// Group g (= wg & 31) = wgs {g, g+32, ..., g+224}, batches 4g..4g+3 split into
// pipelined pairs A={0,1}, B={2,3}: phase A of step t imports h_A(t) published
// one full B-phase earlier -> exchange RTT hidden behind the other pair's
// compute. Member q = wg>>5 owns h elements [32q,32q+32).
// Lane layout: kc = lane&15 (K-chunk of 16), rs = lane>>4; wave w owns local
// rows w*8+rs*2 and +1 -> per-row 16 partials live in 16 lanes of one wave
// -> shfl_xor butterfly reduce (no LDS staging, no reduce barrier).
// h_lds stride-20 per chunk keeps lane-varying ds_read_b128 <=2-way aliased.
// Exchange: epoch-tagged {epoch,h} 8B agent-scope relaxed atomics (round-5
// proven); 2-slot parity, causally race-free.
__global__ __launch_bounds__(1024)
__attribute__((amdgpu_waves_per_eu(4, 4)))
void lstm_coop(
    const float* __restrict__ x,      // [B,T]
    const float* __restrict__ W_ih,   // [1024]
    const float* __restrict__ W_hh,   // [1024,256]
    const float* __restrict__ b_ih,   // [1024]
    const float* __restrict__ b_hh,   // [1024]
    const float* __restrict__ W1,     // [128,256]
    const float* __restrict__ b1,     // [128]
    const float* __restrict__ W2,     // [128]
    const float* __restrict__ b2,     // [1]
    float* __restrict__ out,          // [B]
    u64* __restrict__ hpair)          // [2][BB][HH] {epoch,h}
{
    const int wg  = blockIdx.x;
    const int g   = wg & 31;
    const int q   = wg >> 5;
    const int tid = threadIdx.x;
    const int b0  = 4 * g;

    __shared__ float x_lds[4][TT];        // 8 KB
    __shared__ float h_lds[4][320];       // 5 KB (stride 20 per 16-chunk)
    __shared__ float gates[2][128][2];    // 2 KB
    __shared__ float cc[32][9];           // 1.1 KB (pad 9 -> conflict-free)
    __shared__ float red_lds[4][128];     // 2 KB
    __shared__ float dummy[21504];        // 84 KB -> static LDS >80KB -> 1 wg/CU

    const int w    = tid >> 6;        // wave 0..15
    const int lane = tid & 63;
    const int kc   = lane & 15;       // K-chunk
    const int rs   = lane >> 4;       // row-slot 0..3
    const int rowA = w * 8 + rs * 2;  // local rows
    const int rowB = rowA + 1;
    const int RA = (rowA >> 5) * HH + q * 32 + (rowA & 31);
    const int RB = (rowB >> 5) * HH + q * 32 + (rowB & 31);

    // resident weights: 2 rows x 16 K = 32 VGPRs
    float wa[16], wb[16];
    {
        const float4* pa = reinterpret_cast<const float4*>(W_hh + (size_t)RA * HH + 16 * kc);
        const float4* pb = reinterpret_cast<const float4*>(W_hh + (size_t)RB * HH + 16 * kc);
        #pragma unroll
        for (int k = 0; k < 4; ++k) {
            float4 va = pa[k], vb = pb[k];
            wa[4*k+0] = va.x; wa[4*k+1] = va.y; wa[4*k+2] = va.z; wa[4*k+3] = va.w;
            wb[4*k+0] = vb.x; wb[4*k+1] = vb.y; wb[4*k+2] = vb.z; wb[4*k+3] = vb.w;
        }
    }
    #pragma unroll
    for (int k = 0; k < 16; ++k) {
        asm volatile("" : "+v"(wa[k]));
        asm volatile("" : "+v"(wb[k]));
    }

    // stage x
    #pragma unroll
    for (int u = 0; u < 2; ++u) {
        int idx = tid + u * 1024;
        int m = idx >> 9, j = idx & 511;
        x_lds[m][j] = x[(size_t)(b0 + m) * TT + j];
    }
    // cell constants for element l (batch-independent): 4x wih + 4x bias
    if (tid < 32) {
        #pragma unroll
        for (int G = 0; G < 4; ++G) {
            const int R = G * HH + q * 32 + tid;
            cc[tid][G]     = W_ih[R];
            cc[tid][4 + G] = b_ih[R] + b_hh[R];
        }
    }
    dummy[tid] = 0.0f;

    float cA = 0.0f, cB = 0.0f;       // cell state (tid<64)
    __syncthreads();

#define PHASE(PH, CREG)                                                        \
    do {                                                                       \
        if (tid < 512) {                                                       \
            const int mm = tid >> 8, j = tid & 255;                            \
            u64* src = &hpair[((size_t)(t & 1) * BB + (b0 + PH * 2 + mm)) * HH + j]; \
            u64 v = __hip_atomic_load(src, __ATOMIC_RELAXED, __HIP_MEMORY_SCOPE_AGENT); \
            int sp = 0;                                                        \
            while ((unsigned)(v >> 32) < (unsigned)t) {                        \
                if (++sp > 6) __builtin_amdgcn_s_sleep(1);                     \
                v = __hip_atomic_load(src, __ATOMIC_RELAXED, __HIP_MEMORY_SCOPE_AGENT); \
            }                                                                  \
            h_lds[PH * 2 + mm][20 * (j >> 4) + (j & 15)] = __uint_as_float((unsigned)v); \
        }                                                                      \
        __syncthreads();                                                       \
        float aA0, aB0, aA1, aB1;                                              \
        dot2x16(&h_lds[PH * 2 + 0][20 * kc], wa, wb, aA0, aB0);                \
        dot2x16(&h_lds[PH * 2 + 1][20 * kc], wa, wb, aA1, aB1);                \
        aA0 += __shfl_xor(aA0, 1, 64); aA1 += __shfl_xor(aA1, 1, 64);          \
        aB0 += __shfl_xor(aB0, 1, 64); aB1 += __shfl_xor(aB1, 1, 64);          \
        aA0 += __shfl_xor(aA0, 2, 64); aA1 += __shfl_xor(aA1, 2, 64);          \
        aB0 += __shfl_xor(aB0, 2, 64); aB1 += __shfl_xor(aB1, 2, 64);          \
        aA0 += __shfl_xor(aA0, 4, 64); aA1 += __shfl_xor(aA1, 4, 64);          \
        aB0 += __shfl_xor(aB0, 4, 64); aB1 += __shfl_xor(aB1, 4, 64);          \
        aA0 += __shfl_xor(aA0, 8, 64); aA1 += __shfl_xor(aA1, 8, 64);          \
        aB0 += __shfl_xor(aB0, 8, 64); aB1 += __shfl_xor(aB1, 8, 64);          \
        if (kc < 4) {                                                          \
            const int r = (kc >> 1) ? rowB : rowA;                             \
            const float vv = (kc == 0) ? aA0 : (kc == 1) ? aA1                 \
                           : (kc == 2) ? aB0 : aB1;                            \
            gates[PH][r][kc & 1] = vv;                                         \
        }                                                                      \
        __syncthreads();                                                       \
        if (tid < 64) {                                                        \
            const int mp = tid >> 5, l = tid & 31;                             \
            const int mA = PH * 2 + mp;                                        \
            const float xv = x_lds[mA][t];                                     \
            float ig = gates[PH][     l][mp] + __builtin_fmaf(xv, cc[l][0], cc[l][4]); \
            float fg = gates[PH][32 + l][mp] + __builtin_fmaf(xv, cc[l][1], cc[l][5]); \
            float gg = gates[PH][64 + l][mp] + __builtin_fmaf(xv, cc[l][2], cc[l][6]); \
            float og = gates[PH][96 + l][mp] + __builtin_fmaf(xv, cc[l][3], cc[l][7]); \
            ig = __builtin_amdgcn_rcpf(1.f + __expf(-ig));                     \
            fg = __builtin_amdgcn_rcpf(1.f + __expf(-fg));                     \
            og = __builtin_amdgcn_rcpf(1.f + __expf(-og));                     \
            gg = 2.f * __builtin_amdgcn_rcpf(1.f + __expf(-2.f * gg)) - 1.f;   \
            CREG = __builtin_fmaf(fg, CREG, ig * gg);                          \
            float th = 2.f * __builtin_amdgcn_rcpf(1.f + __expf(-2.f * CREG)) - 1.f; \
            float hn = og * th;                                                \
            u64 pk = ((u64)(unsigned)(t + 1) << 32) | (u64)__float_as_uint(hn);\
            __hip_atomic_store(&hpair[((size_t)((t + 1) & 1) * BB + (b0 + mA)) * HH + (q * 32 + l)], \
                               pk, __ATOMIC_RELAXED, __HIP_MEMORY_SCOPE_AGENT);\
        }                                                                      \
    } while (0)

    for (int t = 0; t < TT; ++t) {
        PHASE(0, cA);
        PHASE(1, cB);
    }
#undef PHASE

    // ---- epilogue: q==0 wg imports final h (epoch TT, slot 0) and runs MLP
    if (q == 0) {
        {
            const int m = tid >> 8, j = tid & 255;
            u64* src = &hpair[((size_t)(TT & 1) * BB + (b0 + m)) * HH + j];
            u64 v = __hip_atomic_load(src, __ATOMIC_RELAXED, __HIP_MEMORY_SCOPE_AGENT);
            int sp = 0;
            while ((unsigned)(v >> 32) < (unsigned)TT) {
                if (++sp > 6) __builtin_amdgcn_s_sleep(1);
                v = __hip_atomic_load(src, __ATOMIC_RELAXED, __HIP_MEMORY_SCOPE_AGENT);
            }
            h_lds[m][20 * (j >> 4) + (j & 15)] = __uint_as_float((unsigned)v);
        }
        __syncthreads();
        if (tid < 512) {
            const int m = tid >> 7, j = tid & 127;
            const float4* w1p = reinterpret_cast<const float4*>(W1 + (size_t)j * HH);
            const float* hb = &h_lds[m][0];
            float s0 = 0.f, s1 = 0.f, s2 = 0.f, s3 = 0.f;
            #pragma unroll
            for (int k4 = 0; k4 < 64; ++k4) {
                float4 wv = w1p[k4];
                float4 hv = *(const float4*)(hb + 20 * (k4 >> 2) + 4 * (k4 & 3));
                s0 = __builtin_fmaf(wv.x, hv.x, s0);
                s1 = __builtin_fmaf(wv.y, hv.y, s1);
                s2 = __builtin_fmaf(wv.z, hv.z, s2);
                s3 = __builtin_fmaf(wv.w, hv.w, s3);
            }
            float rv = fmaxf((s0 + s1) + (s2 + s3) + b1[j], 0.f);
            red_lds[m][j] = rv * W2[j];
        }
        __syncthreads();
        if (tid < 4) {
            float y = b2[0];
            for (int k = 0; k < 128; ++k) y += red_lds[tid][k];
            out[b0 + tid] = y;
        }
    }
}

extern "C" void kernel_launch(void* const* d_in, const int* in_sizes, int n_in,
                              void* d_out, int out_size, void* d_ws, size_t ws_size,
                              hipStream_t stream) {
    const float* x    = (const float*)d_in[0];
    const float* W_ih = (const float*)d_in[1];
    const float* W_hh = (const float*)d_in[2];
    const float* b_ih = (const float*)d_in[3];
    const float* b_hh = (const float*)d_in[4];
    const float* W1   = (const float*)d_in[5];
    const float* b1   = (const float*)d_in[6];
    const float* W2   = (const float*)d_in[7];
    const float* b2   = (const float*)d_in[8];
    float* out  = (float*)d_out;

    u64* hpair = (u64*)d_ws;                    // [2][128][256] x 8B = 512 KB

    // epochs must be 0 at every call (d_ws persists across graph replays)
    (void)hipMemsetAsync(d_ws, 0, (size_t)2 * BB * HH * sizeof(u64), stream);

    void* args[] = {(void*)&x, (void*)&W_ih, (void*)&W_hh, (void*)&b_ih, (void*)&b_hh,
                    (void*)&W1, (void*)&b1, (void*)&W2, (void*)&b2,
                    (void*)&out, (void*)&hpair};
    (void)hipLaunchCooperativeKernel((void*)lstm_coop, dim3(256), dim3(1024), args, 0, stream);
}